// Round 7
// baseline (351.579 us; speedup 1.0000x reference)
//
#include <hip/hip_runtime.h>
#include <hip/hip_fp16.h>
#include <math.h>
#include <stddef.h>

#define D_DIM 128
#define NUM_RBF 20
typedef unsigned short ushort_t;
typedef unsigned int uint_t;
typedef _Float16 h2v __attribute__((ext_vector_type(2)));
constexpr float PI_F = 3.14159265358979323846f;
constexpr float CUT_OFF_F = 5.0f;
constexpr float SILU_SCALE_F = 1.0f / 0.6f;

__device__ __forceinline__ uint_t pack2h(float a, float b) {
  __half2 h2 = __floats2half2_rn(a, b);
  return *reinterpret_cast<uint_t*>(&h2);
}
__device__ __forceinline__ float h2f(ushort_t u) {
  __half h = __ushort_as_half(u);
  return __half2float(h);
}
__device__ __forceinline__ float h2f_lo(uint_t u) { return h2f((ushort_t)(u & 0xffffu)); }
__device__ __forceinline__ float h2f_hi(uint_t u) { return h2f((ushort_t)(u >> 16)); }
__device__ __forceinline__ h2v u2h2(uint_t u) {
  h2v r;
  __builtin_memcpy(&r, &u, 4);
  return r;
}

#if defined(__has_builtin)
#if __has_builtin(__builtin_amdgcn_fdot2)
#define HAVE_FDOT2 1
#endif
#endif

__device__ __forceinline__ float fdot2f(h2v a, h2v b, float c) {
#ifdef HAVE_FDOT2
  return __builtin_amdgcn_fdot2(a, b, c, false);
#else
  return c + (float)a.x * (float)b.x + (float)a.y * (float)b.y;
#endif
}

// ---------------------------------------------------------------------------
// Fused node projection + merged-buffer build.
// s = scaled_silu(X @ W1 + b1) @ W2 + b2.
// Phase-2 output columns are grouped CHAN-MAJOR: thread (c0,r0) owns s
// columns 3*c0 .. 3*c0+11 (chans c0..c0+3, comps 0..2). Epilogue streams
// vf fp32 and writes merged[N][128][6] fp16: {s(3d),s(3d+1),s(3d+2),v0,v1,v2}.
// This replaces the standalone vf_cast kernel (fused into proj's epilogue).
// ---------------------------------------------------------------------------
__global__ __launch_bounds__(256) void proj_kernel(
    const float* __restrict__ X, const float* __restrict__ W1,
    const float* __restrict__ b1, const float* __restrict__ W2,
    const float* __restrict__ b2, const float* __restrict__ vf,
    uint_t* __restrict__ merged, int N) {
  __shared__ float smA[32 * 128];   // xs then hs
  __shared__ float smB[8192];       // W1 chunk (64x128) / W2 chunk (16x384)
  float* xs = smA;
  float* hs = smA;
  float* w1s = smB;
  float* w2c = smB;

  const int t = threadIdx.x;
  const int nb = blockIdx.x * 32;

  {
    const float4* Xv = reinterpret_cast<const float4*>(X);
    float4* xsv = reinterpret_cast<float4*>(xs);
#pragma unroll
    for (int i = 0; i < 4; ++i) {
      int f4 = t + i * 256;
      int node = nb + (f4 >> 5);
      xsv[f4] = (node < N) ? Xv[(size_t)nb * 32 + f4]
                           : make_float4(0.f, 0.f, 0.f, 0.f);
    }
  }
  __syncthreads();

  const int c0 = (t & 31) * 4;   // chan 0..124
  const int r0 = (t >> 5) * 4;   // row 0..28

  // ---- phase 1: h = X @ W1, W1 in 2 chunks of 64 K-rows ----
  float acc1[4][4] = {};
  for (int kc1 = 0; kc1 < 128; kc1 += 64) {
    __syncthreads();
    {
      const float4* W1v = reinterpret_cast<const float4*>(W1);
      float4* wv = reinterpret_cast<float4*>(w1s);
#pragma unroll
      for (int i = 0; i < 8; ++i)
        wv[t + i * 256] = W1v[kc1 * 32 + t + i * 256];
    }
    __syncthreads();
    for (int k = 0; k < 64; k += 4) {
      float xa[4][4];
#pragma unroll
      for (int i = 0; i < 4; ++i) {
        float4 xt =
            *reinterpret_cast<const float4*>(&xs[(r0 + i) * 128 + kc1 + k]);
        xa[i][0] = xt.x; xa[i][1] = xt.y; xa[i][2] = xt.z; xa[i][3] = xt.w;
      }
#pragma unroll
      for (int kk = 0; kk < 4; ++kk) {
        float4 wv = *reinterpret_cast<const float4*>(&w1s[(k + kk) * 128 + c0]);
        float wa[4] = {wv.x, wv.y, wv.z, wv.w};
#pragma unroll
        for (int i = 0; i < 4; ++i)
#pragma unroll
          for (int j = 0; j < 4; ++j) acc1[i][j] += xa[i][kk] * wa[j];
      }
    }
  }
  __syncthreads();

  {
    float b1v[4];
#pragma unroll
    for (int j = 0; j < 4; ++j) b1v[j] = b1[c0 + j];
#pragma unroll
    for (int i = 0; i < 4; ++i) {
#pragma unroll
      for (int j = 0; j < 4; ++j) {
        float h = acc1[i][j] + b1v[j];
        h = h * SILU_SCALE_F / (1.0f + expf(-h));
        hs[(r0 + i) * 128 + c0 + j] = h;
      }
    }
  }

  // ---- phase 2: chan-major columns 3*c0 .. 3*c0+11 ----
  float acc2[4][12];
#pragma unroll
  for (int jj = 0; jj < 12; ++jj) {
    float bv = b2[3 * c0 + jj];
#pragma unroll
    for (int i = 0; i < 4; ++i) acc2[i][jj] = bv;
  }

  for (int kc = 0; kc < 128; kc += 16) {
    __syncthreads();
    {
      const float4* W2v = reinterpret_cast<const float4*>(W2);
      float4* wv = reinterpret_cast<float4*>(w2c);
#pragma unroll
      for (int i = 0; i < 6; ++i)
        wv[t + i * 256] = W2v[(size_t)kc * 96 + t + i * 256];
    }
    __syncthreads();
    for (int kk = 0; kk < 16; ++kk) {
      float xr[4];
#pragma unroll
      for (int i = 0; i < 4; ++i) xr[i] = hs[(r0 + i) * 128 + kc + kk];
      float wa[12];
#pragma unroll
      for (int q = 0; q < 3; ++q) {
        float4 wv =
            *reinterpret_cast<const float4*>(&w2c[kk * 384 + 3 * c0 + 4 * q]);
        wa[4 * q + 0] = wv.x; wa[4 * q + 1] = wv.y;
        wa[4 * q + 2] = wv.z; wa[4 * q + 3] = wv.w;
      }
#pragma unroll
      for (int i = 0; i < 4; ++i)
#pragma unroll
        for (int jj = 0; jj < 12; ++jj) acc2[i][jj] += xr[i] * wa[jj];
    }
  }

  // ---- epilogue: stream vf, write merged [N][128][6] fp16 ----
#pragma unroll
  for (int i = 0; i < 4; ++i) {
    int node = nb + r0 + i;
    if (node < N) {
#pragma unroll
      for (int jc = 0; jc < 4; ++jc) {
        const int chan = c0 + jc;
        const float* vp = vf + ((size_t)node * 128 + chan) * 3;
        const float v0 = vp[0], v1 = vp[1], v2 = vp[2];
        uint_t* mp = merged + ((size_t)node * 128 + chan) * 3;
        mp[0] = pack2h(acc2[i][3 * jc + 0], acc2[i][3 * jc + 1]);
        mp[1] = pack2h(acc2[i][3 * jc + 2], v0);
        mp[2] = pack2h(v1, v2);
      }
    }
  }
}

// ---------------------------------------------------------------------------
// CSR build
// ---------------------------------------------------------------------------
__global__ void zero_kernel(int* __restrict__ p, int n) {
  int i = blockIdx.x * 256 + threadIdx.x;
  if (i < n) p[i] = 0;
}

__global__ void hist_kernel(const int* __restrict__ tgt, int* __restrict__ counts,
                            int E) {
  int e = blockIdx.x * 256 + threadIdx.x;
  if (e < E) atomicAdd(&counts[tgt[e]], 1);
}

__global__ void chunk_sum_kernel(const int* __restrict__ counts,
                                 int* __restrict__ chunk_sums, int N) {
  __shared__ int red[256];
  int b = blockIdx.x, t = threadIdx.x;
  int base = b * 1024 + t * 4;
  int s = 0;
#pragma unroll
  for (int j = 0; j < 4; ++j) s += (base + j < N) ? counts[base + j] : 0;
  red[t] = s;
  __syncthreads();
  for (int off = 128; off > 0; off >>= 1) {
    if (t < off) red[t] += red[t + off];
    __syncthreads();
  }
  if (t == 0) chunk_sums[b] = red[0];
}

__global__ void scan_chunks_kernel(int* __restrict__ chunk_sums,
                                   int* __restrict__ offsets, int nch, int N,
                                   int E) {
  int t = threadIdx.x;  // one wave; nch <= 64
  int v = (t < nch) ? chunk_sums[t] : 0;
  int orig = v;
#pragma unroll
  for (int off = 1; off < 64; off <<= 1) {
    int y = __shfl_up(v, off);
    if (t >= off) v += y;
  }
  if (t < nch) chunk_sums[t] = v - orig;
  if (t == 0) offsets[N] = E;
}

__global__ void scan_block_kernel(const int* __restrict__ counts,
                                  const int* __restrict__ chunk_off,
                                  int* __restrict__ offsets,
                                  int* __restrict__ cursor, int N) {
  __shared__ int part[256];
  int b = blockIdx.x, t = threadIdx.x;
  int base = b * 1024 + t * 4;
  int v[4];
#pragma unroll
  for (int j = 0; j < 4; ++j) v[j] = (base + j < N) ? counts[base + j] : 0;
  int local = v[0] + v[1] + v[2] + v[3];
  part[t] = local;
  __syncthreads();
  for (int off = 1; off < 256; off <<= 1) {
    int x = 0;
    if (t >= off) x = part[t - off];
    __syncthreads();
    if (t >= off) part[t] += x;
    __syncthreads();
  }
  int run = chunk_off[b] + (part[t] - local);
#pragma unroll
  for (int j = 0; j < 4; ++j) {
    if (base + j < N) {
      offsets[base + j] = run;
      cursor[base + j] = run;
      run += v[j];
    }
  }
}

// ---------------------------------------------------------------------------
// Fused edge geometry + CSR scatter. rbf packed fp16 (10 x half2, stride 12
// uints for 16B alignment), dir fp32.
// ---------------------------------------------------------------------------
__global__ void edge_geom_kernel(const float* __restrict__ pos,
                                 const int* __restrict__ src,
                                 const int* __restrict__ tgt,
                                 int* __restrict__ cursor,
                                 float4* __restrict__ dir4_s,
                                 uint_t* __restrict__ rbh_s,
                                 int* __restrict__ src_s, int E) {
  int e = blockIdx.x * 256 + threadIdx.x;
  if (e >= E) return;
  const int sn = src[e];
  const int tn = tgt[e];
  const float rx = pos[tn * 3 + 0] - pos[sn * 3 + 0];
  const float ry = pos[tn * 3 + 1] - pos[sn * 3 + 1];
  const float rz = pos[tn * 3 + 2] - pos[sn * 3 + 2];
  const float dist = sqrtf(rx * rx + ry * ry + rz * rz);
  const float inv = 1.0f / dist;

  const float ang = dist * (PI_F / CUT_OFF_F);
  float s1, c1;
  sincosf(ang, &s1, &c1);
  float sk = s1, ck = c1;
  float rb[NUM_RBF];
  rb[0] = s1 * inv;
#pragma unroll
  for (int r = 1; r < NUM_RBF; ++r) {
    float sn2 = sk * c1 + ck * s1;
    ck = ck * c1 - sk * s1;
    sk = sn2;
    rb[r] = sk * inv;
  }

  const int p = atomicAdd(&cursor[tn], 1);
  dir4_s[p] = make_float4(rx * inv, ry * inv, rz * inv, dist);
  src_s[p] = sn;
  uint_t us[10];
#pragma unroll
  for (int q = 0; q < 10; ++q) us[q] = pack2h(rb[2 * q], rb[2 * q + 1]);
  uint_t* o = rbh_s + (size_t)p * 12;
  *reinterpret_cast<uint4*>(o) = make_uint4(us[0], us[1], us[2], us[3]);
  *reinterpret_cast<uint4*>(o + 4) = make_uint4(us[4], us[5], us[6], us[7]);
  *reinterpret_cast<uint2*>(o + 8) = make_uint2(us[8], us[9]);
}

// ---------------------------------------------------------------------------
// Node gather. Single merged fp16 gather (3 uints, one base) per edge-lane,
// packed-fp16 rbf with v_dot2 filter dot, shfl-broadcast src, x2 ILP.
// ---------------------------------------------------------------------------
#define NODES_PER_BLOCK 8

__device__ __forceinline__ float cutoff_f(float x) {
  return (x < CUT_OFF_F) ? 0.5f * (1.0f + __cosf(x * (PI_F / CUT_OFF_F))) : 0.f;
}

struct EdgeData {
  float4 dir;
  uint_t rbu[10];
  uint_t su[3];
};

__device__ __forceinline__ void load_edge(int idx, int sn, int d,
                                          const uint_t* __restrict__ merged,
                                          const float4* __restrict__ dir4_s,
                                          const uint_t* __restrict__ rbh_s,
                                          EdgeData& ed) {
  ed.dir = dir4_s[idx];
  const uint_t* o = rbh_s + (size_t)idx * 12;
  uint4 u0 = *reinterpret_cast<const uint4*>(o);
  uint4 u1 = *reinterpret_cast<const uint4*>(o + 4);
  uint2 u2 = *reinterpret_cast<const uint2*>(o + 8);
  ed.rbu[0] = u0.x; ed.rbu[1] = u0.y; ed.rbu[2] = u0.z; ed.rbu[3] = u0.w;
  ed.rbu[4] = u1.x; ed.rbu[5] = u1.y; ed.rbu[6] = u1.z; ed.rbu[7] = u1.w;
  ed.rbu[8] = u2.x; ed.rbu[9] = u2.y;
  const uint_t* mp = merged + ((size_t)sn * 128 + d) * 3;
  ed.su[0] = mp[0]; ed.su[1] = mp[1]; ed.su[2] = mp[2];
}

__global__ __launch_bounds__(128) void node_kernel(
    const uint_t* __restrict__ merged, const float4* __restrict__ dir4_s,
    const uint_t* __restrict__ rbh_s, const int* __restrict__ src_s,
    const int* __restrict__ offsets, const float* __restrict__ Wr,
    const float* __restrict__ br, float* __restrict__ out, int N, int E) {
  const int d = threadIdx.x;
  const int lane = d & 63;

  h2v wr0h[10], wr1h[10], wr2h[10];
#pragma unroll
  for (int q = 0; q < 10; ++q) {
    h2v w;
    w.x = (_Float16)Wr[(2 * q) * 384 + 3 * d + 0];
    w.y = (_Float16)Wr[(2 * q + 1) * 384 + 3 * d + 0];
    wr0h[q] = w;
    w.x = (_Float16)Wr[(2 * q) * 384 + 3 * d + 1];
    w.y = (_Float16)Wr[(2 * q + 1) * 384 + 3 * d + 1];
    wr1h[q] = w;
    w.x = (_Float16)Wr[(2 * q) * 384 + 3 * d + 2];
    w.y = (_Float16)Wr[(2 * q + 1) * 384 + 3 * d + 2];
    wr2h[q] = w;
  }
  const float br0 = br[3 * d + 0];
  const float br1 = br[3 * d + 1];
  const float br2 = br[3 * d + 2];

  for (int nn = 0; nn < NODES_PER_BLOCK; ++nn) {
    const int n = blockIdx.x * NODES_PER_BLOCK + nn;
    if (n >= N) break;

    const int start = offsets[n];
    const int end = offsets[n + 1];

    float accs = 0.f, av0 = 0.f, av1 = 0.f, av2 = 0.f;

    for (int base = start; base < end; base += 64) {
      const int m = min(64, end - base);
      int ld = base + lane;
      if (ld >= E) ld = E - 1;
      const int sn_l = src_s[ld];

      int i = 0;
      for (; i + 2 <= m; i += 2) {
        const int sn0 = __shfl(sn_l, i);
        const int sn1 = __shfl(sn_l, i + 1);
        EdgeData e0, e1;
        load_edge(base + i, sn0, d, merged, dir4_s, rbh_s, e0);
        load_edge(base + i + 1, sn1, d, merged, dir4_s, rbh_s, e1);

#pragma unroll
        for (int u = 0; u < 2; ++u) {
          const EdgeData& ed = (u == 0) ? e0 : e1;
          float f0 = br0, f1 = br1, f2 = br2;
#pragma unroll
          for (int q = 0; q < 10; ++q) {
            h2v r = u2h2(ed.rbu[q]);
            f0 = fdot2f(r, wr0h[q], f0);
            f1 = fdot2f(r, wr1h[q], f1);
            f2 = fdot2f(r, wr2h[q], f2);
          }
          f0 = cutoff_f(f0);
          f1 = cutoff_f(f1);
          f2 = cutoff_f(f2);
          const float m0 = h2f_lo(ed.su[0]) * f0;
          const float m1 = h2f_hi(ed.su[0]) * f1;
          const float m2 = h2f_lo(ed.su[1]) * f2;
          accs += m0;
          av0 += m2 * ed.dir.x + m1 * h2f_hi(ed.su[1]);
          av1 += m2 * ed.dir.y + m1 * h2f_lo(ed.su[2]);
          av2 += m2 * ed.dir.z + m1 * h2f_hi(ed.su[2]);
        }
      }
      if (i < m) {
        const int sn0 = __shfl(sn_l, i);
        EdgeData e0;
        load_edge(base + i, sn0, d, merged, dir4_s, rbh_s, e0);
        float f0 = br0, f1 = br1, f2 = br2;
#pragma unroll
        for (int q = 0; q < 10; ++q) {
          h2v r = u2h2(e0.rbu[q]);
          f0 = fdot2f(r, wr0h[q], f0);
          f1 = fdot2f(r, wr1h[q], f1);
          f2 = fdot2f(r, wr2h[q], f2);
        }
        f0 = cutoff_f(f0);
        f1 = cutoff_f(f1);
        f2 = cutoff_f(f2);
        const float m0 = h2f_lo(e0.su[0]) * f0;
        const float m1 = h2f_hi(e0.su[0]) * f1;
        const float m2 = h2f_lo(e0.su[1]) * f2;
        accs += m0;
        av0 += m2 * e0.dir.x + m1 * h2f_hi(e0.su[1]);
        av1 += m2 * e0.dir.y + m1 * h2f_lo(e0.su[2]);
        av2 += m2 * e0.dir.z + m1 * h2f_hi(e0.su[2]);
      }
    }

    out[(size_t)n * 384 + 3 * d + 0] = av0;
    out[(size_t)n * 384 + 3 * d + 1] = av1;
    out[(size_t)n * 384 + 3 * d + 2] = av2;
    out[(size_t)N * 384 + (size_t)n * 128 + d] = accs;
  }
}

// ---------------------------------------------------------------------------
extern "C" void kernel_launch(void* const* d_in, const int* in_sizes, int n_in,
                              void* d_out, int out_size, void* d_ws,
                              size_t ws_size, hipStream_t stream) {
  const float* vf  = (const float*)d_in[0];   // [N,128,3]
  const float* X   = (const float*)d_in[1];   // [N,128]
  const float* pos = (const float*)d_in[2];   // [N,3]
  const int* ei    = (const int*)d_in[3];     // [2,E]
  const float* W1  = (const float*)d_in[4];
  const float* b1  = (const float*)d_in[5];
  const float* W2  = (const float*)d_in[6];
  const float* b2  = (const float*)d_in[7];
  const float* Wr  = (const float*)d_in[8];
  const float* br  = (const float*)d_in[9];

  const int N = in_sizes[1] / D_DIM;
  const int E = in_sizes[3] / 2;
  const int* srcI = ei;
  const int* tgtI = ei + E;
  float* out = (float*)d_out;

  // workspace layout (16B-aligned chunks first)
  char* w = (char*)d_ws;
  float4* dir4_s = (float4*)w;  w += (size_t)E * sizeof(float4);
  uint_t* rbh_s  = (uint_t*)w;  w += (size_t)E * 12 * sizeof(uint_t);
  uint_t* merged = (uint_t*)w;  w += (size_t)N * 128 * 3 * sizeof(uint_t);
  int* src_s     = (int*)w;     w += (size_t)E * sizeof(int);
  int* counts    = (int*)w;     w += (size_t)N * sizeof(int);
  int* offsets   = (int*)w;     w += (size_t)(N + 1) * sizeof(int);
  int* cursor    = (int*)w;     w += (size_t)N * sizeof(int);
  int* chunks    = (int*)w;     w += 64 * sizeof(int);

  const int nch = (N + 1023) / 1024;  // 49 for N=50000

  zero_kernel<<<(N + 255) / 256, 256, 0, stream>>>(counts, N);
  proj_kernel<<<(N + 31) / 32, 256, 0, stream>>>(X, W1, b1, W2, b2, vf, merged,
                                                 N);
  hist_kernel<<<(E + 255) / 256, 256, 0, stream>>>(tgtI, counts, E);
  chunk_sum_kernel<<<nch, 256, 0, stream>>>(counts, chunks, N);
  scan_chunks_kernel<<<1, 64, 0, stream>>>(chunks, offsets, nch, N, E);
  scan_block_kernel<<<nch, 256, 0, stream>>>(counts, chunks, offsets, cursor, N);
  edge_geom_kernel<<<(E + 255) / 256, 256, 0, stream>>>(pos, srcI, tgtI, cursor,
                                                        dir4_s, rbh_s, src_s, E);
  node_kernel<<<(N + NODES_PER_BLOCK - 1) / NODES_PER_BLOCK, 128, 0, stream>>>(
      merged, dir4_s, rbh_s, src_s, offsets, Wr, br, out, N, E);
}